// Round 1
// 423.491 us; speedup vs baseline: 1.3155x; 1.3155x over previous
//
#include <hip/hip_runtime.h>

typedef __bf16 bf16;
typedef __bf16 bf16x8 __attribute__((ext_vector_type(8)));
typedef __bf16 bf16x4 __attribute__((ext_vector_type(4)));
typedef float f32x4 __attribute__((ext_vector_type(4)));

constexpr int BB   = 8;
constexpr int LQ   = 2048;
constexpr int LKV  = 1024;
constexpr int DM   = 1024;   // H*DK
constexpr int DIMG = 512;
constexpr int H    = 16;
constexpr int DK   = 64;

__device__ inline void async16(const bf16* g, bf16* l) {
  __builtin_amdgcn_global_load_lds((const __attribute__((address_space(1))) void*)g,
                                   (__attribute__((address_space(3))) void*)l, 16, 0, 0);
}
__device__ inline float fexp2(float x) { return __builtin_amdgcn_exp2f(x); }

// ---------------- fused fp32 -> bf16 convert for q,k,v ----------------
__global__ __launch_bounds__(256) void cvt_all(const float* __restrict__ q,
                                               const float* __restrict__ k,
                                               const float* __restrict__ v,
                                               bf16* __restrict__ qo,
                                               bf16* __restrict__ ko,
                                               bf16* __restrict__ vo,
                                               int nq4, int nk4) {
  int i = blockIdx.x * 256 + threadIdx.x;
  const float* in;
  bf16* out;
  int idx;
  if (i < nq4) { in = q; out = qo; idx = i; }
  else if (i < nq4 + nk4) { in = k; out = ko; idx = i - nq4; }
  else if (i < nq4 + 2 * nk4) { in = v; out = vo; idx = i - nq4 - nk4; }
  else return;
  const float4 f = ((const float4*)in)[idx];
  bf16x4 o;
  o[0] = (bf16)f.x; o[1] = (bf16)f.y; o[2] = (bf16)f.z; o[3] = (bf16)f.w;
  ((bf16x4*)out)[idx] = o;
}

// ------------- fused weight transposes: W [K,N] fp32 -> WT [N,K] bf16 -------------
__global__ __launch_bounds__(256) void transpose_all(const float* __restrict__ Wq,
                                                     const float* __restrict__ Wk,
                                                     const float* __restrict__ Wv,
                                                     const float* __restrict__ Wo,
                                                     bf16* __restrict__ WqT,
                                                     bf16* __restrict__ WkT,
                                                     bf16* __restrict__ WvT,
                                                     bf16* __restrict__ WoT) {
  const int z = blockIdx.z;
  const float* W;
  bf16* WT;
  int K;
  if (z == 0) { W = Wq; WT = WqT; K = DM; }
  else if (z == 1) { W = Wk; WT = WkT; K = DIMG; }
  else if (z == 2) { W = Wv; WT = WvT; K = DIMG; }
  else { W = Wo; WT = WoT; K = DM; }
  const int N = DM;
  if (blockIdx.x * 64 >= K) return;  // uniform early-out for the 512-row weights

  __shared__ float tile[64][65];
  const int k0 = blockIdx.x * 64, n0 = blockIdx.y * 64;
  const int tx = threadIdx.x & 63, tg = threadIdx.x >> 6;
#pragma unroll
  for (int i = 0; i < 16; ++i) {
    int row = tg * 16 + i;
    tile[row][tx] = W[(size_t)(k0 + row) * N + n0 + tx];
  }
  __syncthreads();
#pragma unroll
  for (int i = 0; i < 16; ++i) {
    int nrow = tg * 16 + i;
    WT[(size_t)(n0 + nrow) * K + k0 + tx] = (bf16)tile[tx][nrow];
  }
}

// ------------- C[M,N] = (A[M,K] @ Bt[N,K]^T + bias) * oscale ; m97-style -------------
// VT_OUT: write bf16 output transposed per-head: Vt[b][h][dk][t] (LKV tokens per batch)
template <typename OutT, bool VT_OUT>
__global__ __launch_bounds__(256) void gemm_bt(const bf16* __restrict__ A,
                                               const bf16* __restrict__ Bt,
                                               const float* __restrict__ bias,
                                               OutT* __restrict__ C,
                                               int M, int N, int K, float oscale) {
  __shared__ __align__(16) bf16 As[128 * 32];
  __shared__ __align__(16) bf16 Bs[128 * 32];

  const int tid = threadIdx.x, lane = tid & 63, wave = tid >> 6;
  const int bm = blockIdx.x, bn = blockIdx.y;
  const int wm = (wave & 1) * 64, wn = (wave >> 1) * 64;
  const int fm = lane & 15, quad = lane >> 4, fk8 = quad * 8;

  f32x4 acc[4][4];
#pragma unroll
  for (int i = 0; i < 4; ++i)
#pragma unroll
    for (int j = 0; j < 4; ++j) {
      f32x4 z = {0.f, 0.f, 0.f, 0.f};
      acc[i][j] = z;
    }

  const int srow = lane >> 2, scol = (lane & 3) * 8;
  const bf16* Ab = A + (size_t)(bm * 128) * K;
  const bf16* Bb = Bt + (size_t)(bn * 128) * K;
  const bf16* ag0 = Ab + (size_t)(wave * 16 + srow) * K + scol;
  const bf16* ag1 = ag0 + (size_t)64 * K;
  const bf16* bg0 = Bb + (size_t)(wave * 16 + srow) * K + scol;
  const bf16* bg1 = bg0 + (size_t)64 * K;
  bf16* la0 = &As[(wave * 16) * 32];
  bf16* la1 = &As[(64 + wave * 16) * 32];
  bf16* lb0 = &Bs[(wave * 16) * 32];
  bf16* lb1 = &Bs[(64 + wave * 16) * 32];

  for (int k0 = 0; k0 < K; k0 += 32) {
    async16(ag0 + k0, la0);
    async16(ag1 + k0, la1);
    async16(bg0 + k0, lb0);
    async16(bg1 + k0, lb1);
    __syncthreads();
    bf16x8 af[4], bfr[4];
#pragma unroll
    for (int i = 0; i < 4; ++i)
      af[i] = *(const bf16x8*)&As[(wm + i * 16 + fm) * 32 + fk8];
#pragma unroll
    for (int j = 0; j < 4; ++j)
      bfr[j] = *(const bf16x8*)&Bs[(wn + j * 16 + fm) * 32 + fk8];
#pragma unroll
    for (int i = 0; i < 4; ++i)
#pragma unroll
      for (int j = 0; j < 4; ++j)
        acc[i][j] = __builtin_amdgcn_mfma_f32_16x16x32_bf16(af[i], bfr[j], acc[i][j], 0, 0, 0);
    __syncthreads();
  }

#pragma unroll
  for (int j = 0; j < 4; ++j) {
    const int col = bn * 128 + wn + j * 16 + fm;
    const float bv = bias[col];
    if constexpr (VT_OUT) {
      const int h = col >> 6, dk = col & 63;
#pragma unroll
      for (int i = 0; i < 4; ++i) {
        const int row = bm * 128 + wm + i * 16 + quad * 4;
        const int b = row >> 10, t = row & 1023;  // LKV = 1024
        bf16x4 o;
#pragma unroll
        for (int r = 0; r < 4; ++r) o[r] = (bf16)((acc[i][j][r] + bv) * oscale);
        *(bf16x4*)&C[(((size_t)(b * H + h) * DK + dk) << 10) + t] = o;
      }
    } else {
#pragma unroll
      for (int i = 0; i < 4; ++i) {
#pragma unroll
        for (int r = 0; r < 4; ++r) {
          const int row = bm * 128 + wm + i * 16 + quad * 4 + r;
          C[(size_t)row * N + col] = (OutT)((acc[i][j][r] + bv) * oscale);
        }
      }
    }
  }
}

// ------------- flash attention, S^T form, LDS-staged K/V (dbuf, swizzled), counted vmcnt -------------
// qh: [B, LQ, H*DK] bf16 PRE-SCALED by 1/sqrt(dk)*log2e. kh: [B, LKV, H*DK] bf16.
// vt: [B][H][DK][LKV] bf16. out: [B, LQ, H*DK].
__global__ __launch_bounds__(256, 3) void attn_kernel(const bf16* __restrict__ qh,
                                                      const bf16* __restrict__ kh,
                                                      const bf16* __restrict__ vt,
                                                      bf16* __restrict__ out) {
  constexpr int NT = LKV / 64;
  // K tile [kv 64][dk 64], V^T tile [dk 64][kv 64]; rows are 128B, 16B-slot XOR-swizzled
  // (slot ^= row&7) -- linear LDS dest + pre-swizzled global source (rule #21).
  __shared__ __align__(16) bf16 Ks[2][64 * 64];
  __shared__ __align__(16) bf16 Vs[2][64 * 64];
  __shared__ __align__(16) bf16 Ps[4][32 * 64];  // wave-private P [q 32][kv 64], same swizzle

  const int tid = threadIdx.x, lane = tid & 63, w = tid >> 6;
  const int fm = lane & 15, quad = lane >> 4;
  const int qt = blockIdx.x, h = blockIdx.y, b = blockIdx.z;
  const int q0 = qt * 128;

  const bf16* qbase = qh + ((size_t)(b * LQ) + q0 + w * 32) * DM + h * DK;
  const bf16* kbase = kh + (size_t)(b * LKV) * DM + h * DK;
  const bf16* vbase = vt + (size_t)(b * H + h) * DK * LKV;

  // Q fragments (B-operand): lane holds Q[q = w*32 + i*16 + fm][k = kg*32 + quad*8 ..+7]
  bf16x8 qf[2][2];
#pragma unroll
  for (int i = 0; i < 2; ++i)
#pragma unroll
    for (int kg = 0; kg < 2; ++kg)
      qf[i][kg] = *(const bf16x8*)&qbase[(size_t)(i * 16 + fm) * DM + kg * 32 + quad * 8];

  const int srow = lane >> 3, sslot = lane & 7;
  const int fs = fm & 7;  // read-side swizzle XOR (row & 7 == fm & 7 for all our reads)

  // cooperative stage of tile t into buffer bf: wave w covers rows [w*16, w*16+16)
  // of both K (kv rows) and V^T (dk rows); 4 global_load_lds per wave per tile.
  auto stage = [&](int t, int bf) {
#pragma unroll
    for (int c = 0; c < 2; ++c) {
      const int r0 = w * 16 + c * 8;
      const int row = r0 + srow;
      const int gs = (sslot ^ (row & 7)) << 3;  // pre-swizzled 16B-slot in global
      async16(kbase + (size_t)(t * 64 + row) * DM + gs, &Ks[bf][r0 * 64]);
      async16(vbase + (size_t)row * LKV + t * 64 + gs, &Vs[bf][r0 * 64]);
    }
  };

  stage(0, 0);
  stage(1, 1);

  float row_m[2] = {-1e30f, -1e30f}, row_l[2] = {0.f, 0.f};
  f32x4 o_acc[2][4];
#pragma unroll
  for (int i = 0; i < 2; ++i)
#pragma unroll
    for (int jd = 0; jd < 4; ++jd) {
      f32x4 z = {0.f, 0.f, 0.f, 0.f};
      o_acc[i][jd] = z;
    }

  bf16* Pw = Ps[w];

#pragma unroll 2
  for (int t = 0; t < NT; ++t) {
    // counted vmcnt: leave next tile's 4 staging loads in flight, ensure tile t's done;
    // barrier then publishes all waves' staged rows.
    asm volatile("s_waitcnt vmcnt(4)" ::: "memory");
    __builtin_amdgcn_s_barrier();
    __builtin_amdgcn_sched_barrier(0);
    const bf16* Kb = Ks[t & 1];
    const bf16* Vb = Vs[t & 1];

    // ---- S^T = K Q^T from LDS ----
    f32x4 s[4][2];
#pragma unroll
    for (int m = 0; m < 4; ++m)
#pragma unroll
      for (int i = 0; i < 2; ++i) {
        f32x4 z = {0.f, 0.f, 0.f, 0.f};
        s[m][i] = z;
      }
    __builtin_amdgcn_s_setprio(1);
#pragma unroll
    for (int kg = 0; kg < 2; ++kg)
#pragma unroll
      for (int m = 0; m < 4; ++m) {
        const bf16x8 kf =
            *(const bf16x8*)&Kb[(m * 16 + fm) * 64 + (((kg * 4 + quad) ^ fs) << 3)];
#pragma unroll
        for (int i = 0; i < 2; ++i)
          s[m][i] = __builtin_amdgcn_mfma_f32_16x16x32_bf16(kf, qf[i][kg], s[m][i], 0, 0, 0);
      }
    __builtin_amdgcn_s_setprio(0);

    // ---- online softmax (s already scaled to log2 domain by q-proj) ----
#pragma unroll
    for (int i = 0; i < 2; ++i) {
      float pm[4];
#pragma unroll
      for (int m = 0; m < 4; ++m)
        pm[m] = fmaxf(fmaxf(s[m][i][0], s[m][i][1]), fmaxf(s[m][i][2], s[m][i][3]));
      float mt = fmaxf(fmaxf(pm[0], pm[1]), fmaxf(pm[2], pm[3]));
      mt = fmaxf(mt, __shfl_xor(mt, 16));
      mt = fmaxf(mt, __shfl_xor(mt, 32));
      float alpha = 1.f;
      // defer-max (T13): only rescale when some column's max grew by > 8 (p <= 2^8)
      if (!__all(mt <= row_m[i] + 8.0f)) {
        const float nm = fmaxf(row_m[i], mt);
        alpha = fexp2(row_m[i] - nm);
        row_m[i] = nm;
#pragma unroll
        for (int r = 0; r < 4; ++r) {
          const float a_o = __shfl(alpha, quad * 4 + r);
#pragma unroll
          for (int jd = 0; jd < 4; ++jd) o_acc[i][jd][r] *= a_o;
        }
      }
      const float mi = row_m[i];
      float pp[4];
#pragma unroll
      for (int m = 0; m < 4; ++m) {
#pragma unroll
        for (int r = 0; r < 4; ++r) s[m][i][r] = fexp2(s[m][i][r] - mi);
        pp[m] = (s[m][i][0] + s[m][i][1]) + (s[m][i][2] + s[m][i][3]);
      }
      float ps = (pp[0] + pp[1]) + (pp[2] + pp[3]);
      ps += __shfl_xor(ps, 16);
      ps += __shfl_xor(ps, 32);
      row_l[i] = row_l[i] * alpha + ps;
    }

    // ---- P: C-layout [kv][q] -> LDS [q][kv] (wave-private, swizzled, in-order DS) ----
#pragma unroll
    for (int i = 0; i < 2; ++i)
#pragma unroll
      for (int m = 0; m < 4; ++m) {
        bf16x4 p4;
#pragma unroll
        for (int r = 0; r < 4; ++r) p4[r] = (bf16)s[m][i][r];
        *(bf16x4*)&Pw[(i * 16 + fm) * 64 + (((m * 2 + (quad >> 1)) ^ fs) << 3) +
                      ((quad & 1) << 2)] = p4;
      }

    // ---- O += P V : A-frag from P-LDS, B-frag from V-LDS ----
    __builtin_amdgcn_s_setprio(1);
#pragma unroll
    for (int kg = 0; kg < 2; ++kg) {
      bf16x8 pf[2];
#pragma unroll
      for (int i = 0; i < 2; ++i)
        pf[i] = *(const bf16x8*)&Pw[(i * 16 + fm) * 64 + (((kg * 4 + quad) ^ fs) << 3)];
#pragma unroll
      for (int jd = 0; jd < 4; ++jd) {
        const bf16x8 vfr =
            *(const bf16x8*)&Vb[(jd * 16 + fm) * 64 + (((kg * 4 + quad) ^ fs) << 3)];
#pragma unroll
        for (int i = 0; i < 2; ++i)
          o_acc[i][jd] = __builtin_amdgcn_mfma_f32_16x16x32_bf16(pf[i], vfr, o_acc[i][jd], 0, 0, 0);
      }
    }
    __builtin_amdgcn_s_setprio(0);

    // all waves done reading buf[t&1]; then refill it with tile t+2.
    __builtin_amdgcn_sched_barrier(0);
    __builtin_amdgcn_s_barrier();
    __builtin_amdgcn_sched_barrier(0);
    if (t < NT - 1) {
      // t == NT-2 restages the last tile redundantly (into the dead buffer) so the
      // loop-top vmcnt(4) accounting stays uniform.
      const int tn = (t + 2 < NT) ? (t + 2) : (NT - 1);
      stage(tn, t & 1);
    }
  }
  asm volatile("s_waitcnt vmcnt(0)" ::: "memory");  // drain before LDS dealloc/endpgm

  // ---- epilogue: normalize, store natural [B,LQ,H*DK] ----
  const float linv0 = 1.0f / row_l[0], linv1 = 1.0f / row_l[1];
  bf16* obase = out + ((size_t)(b * LQ) + q0 + w * 32) * DM + h * DK;
#pragma unroll
  for (int i = 0; i < 2; ++i) {
    const float li = i ? linv1 : linv0;
#pragma unroll
    for (int r = 0; r < 4; ++r) {
      const float lo = __shfl(li, quad * 4 + r);
#pragma unroll
      for (int jd = 0; jd < 4; ++jd)
        obase[(size_t)(i * 16 + quad * 4 + r) * DM + jd * 16 + fm] =
            (bf16)(o_acc[i][jd][r] * lo);
    }
  }
}

extern "C" void kernel_launch(void* const* d_in, const int* in_sizes, int n_in,
                              void* d_out, int out_size, void* d_ws, size_t ws_size,
                              hipStream_t stream) {
  const float* q  = (const float*)d_in[0];
  const float* k  = (const float*)d_in[1];
  const float* v  = (const float*)d_in[2];
  const float* Wq = (const float*)d_in[3];
  const float* bq = (const float*)d_in[4];
  const float* Wk = (const float*)d_in[5];
  const float* bk = (const float*)d_in[6];
  const float* Wv = (const float*)d_in[7];
  const float* bv = (const float*)d_in[8];
  const float* Wo = (const float*)d_in[9];
  const float* bo = (const float*)d_in[10];
  float* out = (float*)d_out;

  char* ws = (char*)d_ws;
  size_t off = 0;
  auto alloc = [&](size_t bytes) -> void* {
    void* p = ws + off;
    off += (bytes + 255) & ~(size_t)255;
    return p;
  };

  const size_t nq = (size_t)BB * LQ * DM;
  const size_t nk = (size_t)BB * LKV * DIMG;
  const size_t nkh = (size_t)BB * LKV * DM;

  bf16* qbf = (bf16*)alloc(nq * 2);  // reused as attn_out after q-proj
  bf16* kbf = (bf16*)alloc(nk * 2);
  bf16* vbf = (bf16*)alloc(nk * 2);
  bf16* WqT = (bf16*)alloc((size_t)DM * DM * 2);
  bf16* WkT = (bf16*)alloc((size_t)DM * DIMG * 2);
  bf16* WvT = (bf16*)alloc((size_t)DM * DIMG * 2);
  bf16* WoT = (bf16*)alloc((size_t)DM * DM * 2);
  bf16* qh  = (bf16*)alloc(nq * 2);
  bf16* kh  = (bf16*)alloc(nkh * 2);
  bf16* Vt  = (bf16*)alloc(nkh * 2);  // [B][H][DK][LKV]
  bf16* attn_out = qbf;

  const int nq4 = (int)(nq / 4), nk4 = (int)(nk / 4);
  cvt_all<<<(nq4 + 2 * nk4 + 255) / 256, 256, 0, stream>>>(q, k, v, qbf, kbf, vbf, nq4, nk4);

  transpose_all<<<dim3(DM / 64, DM / 64, 4), 256, 0, stream>>>(Wq, Wk, Wv, Wo, WqT, WkT, WvT, WoT);

  // q-proj pre-scaled by 1/sqrt(DK) * log2(e): attn softmax runs in log2 domain with no
  // per-element scaling.
  const float QSCALE = 0.125f * 1.44269504f;
  gemm_bt<bf16, false><<<dim3(BB * LQ / 128, DM / 128), 256, 0, stream>>>(
      qbf, WqT, bq, qh, BB * LQ, DM, DM, QSCALE);
  gemm_bt<bf16, false><<<dim3(BB * LKV / 128, DM / 128), 256, 0, stream>>>(
      kbf, WkT, bk, kh, BB * LKV, DM, DIMG, 1.0f);
  gemm_bt<bf16, true><<<dim3(BB * LKV / 128, DM / 128), 256, 0, stream>>>(
      vbf, WvT, bv, Vt, BB * LKV, DM, DIMG, 1.0f);

  attn_kernel<<<dim3(LQ / 128, H, BB), 256, 0, stream>>>(qh, kh, Vt, attn_out);

  gemm_bt<float, false><<<dim3(BB * LQ / 128, DM / 128), 256, 0, stream>>>(
      attn_out, WoT, bo, out, BB * LQ, DM, DM, 1.0f);
}

// Round 2
// 399.399 us; speedup vs baseline: 1.3948x; 1.0603x over previous
//
#include <hip/hip_runtime.h>

typedef __bf16 bf16;
typedef __bf16 bf16x8 __attribute__((ext_vector_type(8)));
typedef __bf16 bf16x4 __attribute__((ext_vector_type(4)));
typedef float f32x4 __attribute__((ext_vector_type(4)));

constexpr int BB   = 8;
constexpr int LQ   = 2048;
constexpr int LKV  = 1024;
constexpr int DM   = 1024;   // H*DK
constexpr int DIMG = 512;
constexpr int H    = 16;
constexpr int DK   = 64;

__device__ inline void async16(const bf16* g, bf16* l) {
  __builtin_amdgcn_global_load_lds((const __attribute__((address_space(1))) void*)g,
                                   (__attribute__((address_space(3))) void*)l, 16, 0, 0);
}
__device__ inline float fexp2(float x) { return __builtin_amdgcn_exp2f(x); }

// ---------------- fused fp32 -> bf16 convert for q,k,v ----------------
__global__ __launch_bounds__(256) void cvt_all(const float* __restrict__ q,
                                               const float* __restrict__ k,
                                               const float* __restrict__ v,
                                               bf16* __restrict__ qo,
                                               bf16* __restrict__ ko,
                                               bf16* __restrict__ vo,
                                               int nq4, int nk4) {
  int i = blockIdx.x * 256 + threadIdx.x;
  const float* in;
  bf16* out;
  int idx;
  if (i < nq4) { in = q; out = qo; idx = i; }
  else if (i < nq4 + nk4) { in = k; out = ko; idx = i - nq4; }
  else if (i < nq4 + 2 * nk4) { in = v; out = vo; idx = i - nq4 - nk4; }
  else return;
  const float4 f = ((const float4*)in)[idx];
  bf16x4 o;
  o[0] = (bf16)f.x; o[1] = (bf16)f.y; o[2] = (bf16)f.z; o[3] = (bf16)f.w;
  ((bf16x4*)out)[idx] = o;
}

// ------------- fused weight transposes: W [K,N] fp32 -> WT [N,K] bf16 -------------
__global__ __launch_bounds__(256) void transpose_all(const float* __restrict__ Wq,
                                                     const float* __restrict__ Wk,
                                                     const float* __restrict__ Wv,
                                                     const float* __restrict__ Wo,
                                                     bf16* __restrict__ WqT,
                                                     bf16* __restrict__ WkT,
                                                     bf16* __restrict__ WvT,
                                                     bf16* __restrict__ WoT) {
  const int z = blockIdx.z;
  const float* W;
  bf16* WT;
  int K;
  if (z == 0) { W = Wq; WT = WqT; K = DM; }
  else if (z == 1) { W = Wk; WT = WkT; K = DIMG; }
  else if (z == 2) { W = Wv; WT = WvT; K = DIMG; }
  else { W = Wo; WT = WoT; K = DM; }
  const int N = DM;
  if (blockIdx.x * 64 >= K) return;  // uniform early-out for the 512-row weights

  __shared__ float tile[64][65];
  const int k0 = blockIdx.x * 64, n0 = blockIdx.y * 64;
  const int tx = threadIdx.x & 63, tg = threadIdx.x >> 6;
#pragma unroll
  for (int i = 0; i < 16; ++i) {
    int row = tg * 16 + i;
    tile[row][tx] = W[(size_t)(k0 + row) * N + n0 + tx];
  }
  __syncthreads();
#pragma unroll
  for (int i = 0; i < 16; ++i) {
    int nrow = tg * 16 + i;
    WT[(size_t)(n0 + nrow) * K + k0 + tx] = (bf16)tile[tx][nrow];
  }
}

// ------------- C[M,N] = (A[M,K] @ Bt[N,K]^T + bias) * oscale -------------
// 2-phase double-buffered pipeline (T3-minimal): stage(t+1) before compute(t),
// ONE __syncthreads per K-step (drains vmcnt; publishes next buffer; protects reuse).
// VT_OUT: write bf16 output transposed per-head: Vt[b][h][dk][t] (LKV tokens per batch)
template <typename OutT, bool VT_OUT>
__device__ __forceinline__ void gemm_body(const bf16* __restrict__ A,
                                          const bf16* __restrict__ Bt,
                                          const float* __restrict__ bias,
                                          OutT* __restrict__ C,
                                          int N, int K, float oscale, int bm, int bn,
                                          bf16* As, bf16* Bs) {
  const int tid = threadIdx.x, lane = tid & 63, wave = tid >> 6;
  const int wm = (wave & 1) * 64, wn = (wave >> 1) * 64;
  const int fm = lane & 15, quad = lane >> 4, fk8 = quad * 8;

  f32x4 acc[4][4];
#pragma unroll
  for (int i = 0; i < 4; ++i)
#pragma unroll
    for (int j = 0; j < 4; ++j) {
      f32x4 z = {0.f, 0.f, 0.f, 0.f};
      acc[i][j] = z;
    }

  const int srow = lane >> 2, scol = (lane & 3) * 8;
  const bf16* ag0 = A + (size_t)(bm * 128 + wave * 16 + srow) * K + scol;
  const bf16* ag1 = ag0 + (size_t)64 * K;
  const bf16* bg0 = Bt + (size_t)(bn * 128 + wave * 16 + srow) * K + scol;
  const bf16* bg1 = bg0 + (size_t)64 * K;
  bf16* la0 = As + (wave * 16) * 32;
  bf16* la1 = As + (64 + wave * 16) * 32;
  bf16* lb0 = Bs + (wave * 16) * 32;
  bf16* lb1 = Bs + (64 + wave * 16) * 32;

  const int KT = K >> 5;
  // prologue: stage tile 0 into buffer 0
  async16(ag0, la0);
  async16(ag1, la1);
  async16(bg0, lb0);
  async16(bg1, lb1);
  __syncthreads();

  for (int t = 0; t < KT; ++t) {
    const int cur = (t & 1) * (128 * 32);
    if (t + 1 < KT) {
      const int nxt = ((t + 1) & 1) * (128 * 32);
      const int k0 = (t + 1) * 32;
      async16(ag0 + k0, la0 + nxt);
      async16(ag1 + k0, la1 + nxt);
      async16(bg0 + k0, lb0 + nxt);
      async16(bg1 + k0, lb1 + nxt);
    }
    bf16x8 af[4], bfr[4];
#pragma unroll
    for (int i = 0; i < 4; ++i)
      af[i] = *(const bf16x8*)&As[cur + (wm + i * 16 + fm) * 32 + fk8];
#pragma unroll
    for (int j = 0; j < 4; ++j)
      bfr[j] = *(const bf16x8*)&Bs[cur + (wn + j * 16 + fm) * 32 + fk8];
#pragma unroll
    for (int i = 0; i < 4; ++i)
#pragma unroll
      for (int j = 0; j < 4; ++j)
        acc[i][j] = __builtin_amdgcn_mfma_f32_16x16x32_bf16(af[i], bfr[j], acc[i][j], 0, 0, 0);
    __syncthreads();  // drains vmcnt(0): next buffer staged; all reads of cur done
  }

#pragma unroll
  for (int j = 0; j < 4; ++j) {
    const int col = bn * 128 + wn + j * 16 + fm;
    const float bv = bias[col];
    if constexpr (VT_OUT) {
      const int h = col >> 6, dk = col & 63;
#pragma unroll
      for (int i = 0; i < 4; ++i) {
        const int row = bm * 128 + wm + i * 16 + quad * 4;
        const int b = row >> 10, t = row & 1023;  // LKV = 1024
        bf16x4 o;
#pragma unroll
        for (int r = 0; r < 4; ++r) o[r] = (bf16)((acc[i][j][r] + bv) * oscale);
        *(bf16x4*)&C[(((size_t)(b * H + h) * DK + dk) << 10) + t] = o;
      }
    } else {
#pragma unroll
      for (int i = 0; i < 4; ++i) {
#pragma unroll
        for (int r = 0; r < 4; ++r) {
          const int row = bm * 128 + wm + i * 16 + quad * 4 + r;
          C[(size_t)row * N + col] = (OutT)((acc[i][j][r] + bv) * oscale);
        }
      }
    }
  }
}

// single GEMM, 1-D grid, bijective XCD chunk swizzle, bn-fastest decode
template <typename OutT>
__global__ __launch_bounds__(256) void gemm_one(const bf16* __restrict__ A,
                                                const bf16* __restrict__ Bt,
                                                const float* __restrict__ bias,
                                                OutT* __restrict__ C,
                                                int N, int K, float oscale) {
  __shared__ __align__(16) bf16 As[2 * 128 * 32];
  __shared__ __align__(16) bf16 Bs[2 * 128 * 32];
  const int cpx = gridDim.x >> 3;  // grid % 8 == 0 for all our launches
  const int wg = ((int)blockIdx.x & 7) * cpx + ((int)blockIdx.x >> 3);
  const int nbn = N >> 7;
  gemm_body<OutT, false>(A, Bt, bias, C, N, K, oscale, wg / nbn, wg % nbn, As, Bs);
}

// fused K-proj + V-proj (each alone fills only half the machine)
__global__ __launch_bounds__(256) void gemm_kv(const bf16* __restrict__ kbf,
                                               const bf16* __restrict__ WkT,
                                               const float* __restrict__ bk,
                                               bf16* __restrict__ kh,
                                               const bf16* __restrict__ vbf,
                                               const bf16* __restrict__ WvT,
                                               const float* __restrict__ bv,
                                               bf16* __restrict__ Vt) {
  __shared__ __align__(16) bf16 As[2 * 128 * 32];
  __shared__ __align__(16) bf16 Bs[2 * 128 * 32];
  const int cpx = gridDim.x >> 3;
  const int wg = ((int)blockIdx.x & 7) * cpx + ((int)blockIdx.x >> 3);
  const int bn = wg & 7;            // nbn = 8
  const int rest = wg >> 3;         // 0..127
  const int bm = rest & 63;         // M = 8192 -> 64 row-blocks
  if (rest < 64)
    gemm_body<bf16, false>(kbf, WkT, bk, kh, DM, DIMG, 1.0f, bm, bn, As, Bs);
  else
    gemm_body<bf16, true>(vbf, WvT, bv, Vt, DM, DIMG, 1.0f, bm, bn, As, Bs);
}

// ------------- flash attention, S^T form, LDS-staged K/V (dbuf, swizzled), counted vmcnt -------------
// 512 threads (8 waves x 32 q-rows = 256 q-rows/block): 2 blocks/CU = 16 waves/CU,
// K/V staged once per 256 q-rows. qh PRE-SCALED by 1/sqrt(dk)*log2e.
__global__ __launch_bounds__(512, 4) void attn_kernel(const bf16* __restrict__ qh,
                                                      const bf16* __restrict__ kh,
                                                      const bf16* __restrict__ vt,
                                                      bf16* __restrict__ out) {
  constexpr int NT = LKV / 64;
  // K tile [kv 64][dk 64], V^T tile [dk 64][kv 64]; 128B rows, 16B-slot XOR-swizzled
  // (slot ^= row&7): linear LDS dest + pre-swizzled global source (rule #21).
  __shared__ __align__(16) bf16 Ks[2][64 * 64];
  __shared__ __align__(16) bf16 Vs[2][64 * 64];
  __shared__ __align__(16) bf16 Ps[8][32 * 64];  // wave-private P [q 32][kv 64], same swizzle

  const int tid = threadIdx.x, lane = tid & 63, w = tid >> 6;  // w 0..7
  const int fm = lane & 15, quad = lane >> 4;
  const int qt = blockIdx.x, h = blockIdx.y, b = blockIdx.z;
  const int q0 = qt * 256;

  const bf16* qbase = qh + ((size_t)(b * LQ) + q0 + w * 32) * DM + h * DK;
  const bf16* kbase = kh + (size_t)(b * LKV) * DM + h * DK;
  const bf16* vbase = vt + (size_t)(b * H + h) * DK * LKV;

  // Q fragments (B-operand): lane holds Q[q = w*32 + i*16 + fm][k = kg*32 + quad*8 ..+7]
  bf16x8 qf[2][2];
#pragma unroll
  for (int i = 0; i < 2; ++i)
#pragma unroll
    for (int kg = 0; kg < 2; ++kg)
      qf[i][kg] = *(const bf16x8*)&qbase[(size_t)(i * 16 + fm) * DM + kg * 32 + quad * 8];

  const int srow = lane >> 3, sslot = lane & 7;
  const int fs = fm & 7;  // read-side swizzle XOR (row & 7 == fm & 7 for all our reads)

  // cooperative stage of tile t into buffer bf: wave w covers rows [w*8, w*8+8)
  // of both K (kv rows) and V^T (dk rows); 2 global_load_lds per wave per tile.
  auto stage = [&](int t, int bf) {
    const int r0 = w * 8;
    const int row = r0 + srow;
    const int gs = (sslot ^ (row & 7)) << 3;  // pre-swizzled 16B-slot in global
    async16(kbase + (size_t)(t * 64 + row) * DM + gs, &Ks[bf][r0 * 64]);
    async16(vbase + (size_t)row * LKV + t * 64 + gs, &Vs[bf][r0 * 64]);
  };

  stage(0, 0);
  stage(1, 1);

  float row_m[2] = {-1e30f, -1e30f}, row_l[2] = {0.f, 0.f};
  f32x4 o_acc[2][4];
#pragma unroll
  for (int i = 0; i < 2; ++i)
#pragma unroll
    for (int jd = 0; jd < 4; ++jd) {
      f32x4 z = {0.f, 0.f, 0.f, 0.f};
      o_acc[i][jd] = z;
    }

  bf16* Pw = Ps[w];

#pragma unroll 2
  for (int t = 0; t < NT; ++t) {
    // counted vmcnt: leave next tile's 2 staging loads in flight, ensure tile t's done;
    // barrier then publishes all waves' staged rows.
    asm volatile("s_waitcnt vmcnt(2)" ::: "memory");
    __builtin_amdgcn_s_barrier();
    __builtin_amdgcn_sched_barrier(0);
    const bf16* Kb = Ks[t & 1];
    const bf16* Vb = Vs[t & 1];

    // ---- S^T = K Q^T from LDS ----
    f32x4 s[4][2];
#pragma unroll
    for (int m = 0; m < 4; ++m)
#pragma unroll
      for (int i = 0; i < 2; ++i) {
        f32x4 z = {0.f, 0.f, 0.f, 0.f};
        s[m][i] = z;
      }
    __builtin_amdgcn_s_setprio(1);
#pragma unroll
    for (int kg = 0; kg < 2; ++kg)
#pragma unroll
      for (int m = 0; m < 4; ++m) {
        const bf16x8 kf =
            *(const bf16x8*)&Kb[(m * 16 + fm) * 64 + (((kg * 4 + quad) ^ fs) << 3)];
#pragma unroll
        for (int i = 0; i < 2; ++i)
          s[m][i] = __builtin_amdgcn_mfma_f32_16x16x32_bf16(kf, qf[i][kg], s[m][i], 0, 0, 0);
      }
    __builtin_amdgcn_s_setprio(0);

    // ---- online softmax (log2 domain; scale folded into q-proj) ----
#pragma unroll
    for (int i = 0; i < 2; ++i) {
      float pm[4];
#pragma unroll
      for (int m = 0; m < 4; ++m)
        pm[m] = fmaxf(fmaxf(s[m][i][0], s[m][i][1]), fmaxf(s[m][i][2], s[m][i][3]));
      float mt = fmaxf(fmaxf(pm[0], pm[1]), fmaxf(pm[2], pm[3]));
      mt = fmaxf(mt, __shfl_xor(mt, 16));
      mt = fmaxf(mt, __shfl_xor(mt, 32));
      float alpha = 1.f;
      // defer-max (T13): only rescale when some column's max grew by > 8 (p <= 2^8)
      if (!__all(mt <= row_m[i] + 8.0f)) {
        const float nm = fmaxf(row_m[i], mt);
        alpha = fexp2(row_m[i] - nm);
        row_m[i] = nm;
#pragma unroll
        for (int r = 0; r < 4; ++r) {
          const float a_o = __shfl(alpha, quad * 4 + r);
#pragma unroll
          for (int jd = 0; jd < 4; ++jd) o_acc[i][jd][r] *= a_o;
        }
      }
      const float mi = row_m[i];
      float pp[4];
#pragma unroll
      for (int m = 0; m < 4; ++m) {
#pragma unroll
        for (int r = 0; r < 4; ++r) s[m][i][r] = fexp2(s[m][i][r] - mi);
        pp[m] = (s[m][i][0] + s[m][i][1]) + (s[m][i][2] + s[m][i][3]);
      }
      float ps = (pp[0] + pp[1]) + (pp[2] + pp[3]);
      ps += __shfl_xor(ps, 16);
      ps += __shfl_xor(ps, 32);
      row_l[i] = row_l[i] * alpha + ps;
    }

    // ---- P: C-layout [kv][q] -> LDS [q][kv] (wave-private, swizzled, in-order DS) ----
#pragma unroll
    for (int i = 0; i < 2; ++i)
#pragma unroll
      for (int m = 0; m < 4; ++m) {
        bf16x4 p4;
#pragma unroll
        for (int r = 0; r < 4; ++r) p4[r] = (bf16)s[m][i][r];
        *(bf16x4*)&Pw[(i * 16 + fm) * 64 + (((m * 2 + (quad >> 1)) ^ fs) << 3) +
                      ((quad & 1) << 2)] = p4;
      }

    // ---- O += P V : A-frag from P-LDS, B-frag from V-LDS ----
    __builtin_amdgcn_s_setprio(1);
#pragma unroll
    for (int kg = 0; kg < 2; ++kg) {
      bf16x8 pf[2];
#pragma unroll
      for (int i = 0; i < 2; ++i)
        pf[i] = *(const bf16x8*)&Pw[(i * 16 + fm) * 64 + (((kg * 4 + quad) ^ fs) << 3)];
#pragma unroll
      for (int jd = 0; jd < 4; ++jd) {
        const bf16x8 vfr =
            *(const bf16x8*)&Vb[(jd * 16 + fm) * 64 + (((kg * 4 + quad) ^ fs) << 3)];
#pragma unroll
        for (int i = 0; i < 2; ++i)
          o_acc[i][jd] = __builtin_amdgcn_mfma_f32_16x16x32_bf16(pf[i], vfr, o_acc[i][jd], 0, 0, 0);
      }
    }
    __builtin_amdgcn_s_setprio(0);

    // all waves done reading buf[t&1]; then refill it with tile t+2.
    __builtin_amdgcn_sched_barrier(0);
    __builtin_amdgcn_s_barrier();
    __builtin_amdgcn_sched_barrier(0);
    if (t < NT - 1) {
      // t == NT-2 restages the last tile redundantly (into the dead buffer) so the
      // loop-top vmcnt(2) accounting stays uniform.
      const int tn = (t + 2 < NT) ? (t + 2) : (NT - 1);
      stage(tn, t & 1);
    }
  }
  asm volatile("s_waitcnt vmcnt(0)" ::: "memory");  // drain before LDS dealloc/endpgm

  // ---- epilogue: normalize, store natural [B,LQ,H*DK] ----
  const float linv0 = 1.0f / row_l[0], linv1 = 1.0f / row_l[1];
  bf16* obase = out + ((size_t)(b * LQ) + q0 + w * 32) * DM + h * DK;
#pragma unroll
  for (int i = 0; i < 2; ++i) {
    const float li = i ? linv1 : linv0;
#pragma unroll
    for (int r = 0; r < 4; ++r) {
      const float lo = __shfl(li, quad * 4 + r);
#pragma unroll
      for (int jd = 0; jd < 4; ++jd)
        obase[(size_t)(i * 16 + quad * 4 + r) * DM + jd * 16 + fm] =
            (bf16)(o_acc[i][jd][r] * lo);
    }
  }
}

extern "C" void kernel_launch(void* const* d_in, const int* in_sizes, int n_in,
                              void* d_out, int out_size, void* d_ws, size_t ws_size,
                              hipStream_t stream) {
  const float* q  = (const float*)d_in[0];
  const float* k  = (const float*)d_in[1];
  const float* v  = (const float*)d_in[2];
  const float* Wq = (const float*)d_in[3];
  const float* bq = (const float*)d_in[4];
  const float* Wk = (const float*)d_in[5];
  const float* bk = (const float*)d_in[6];
  const float* Wv = (const float*)d_in[7];
  const float* bv = (const float*)d_in[8];
  const float* Wo = (const float*)d_in[9];
  const float* bo = (const float*)d_in[10];
  float* out = (float*)d_out;

  char* ws = (char*)d_ws;
  size_t off = 0;
  auto alloc = [&](size_t bytes) -> void* {
    void* p = ws + off;
    off += (bytes + 255) & ~(size_t)255;
    return p;
  };

  const size_t nq = (size_t)BB * LQ * DM;
  const size_t nk = (size_t)BB * LKV * DIMG;
  const size_t nkh = (size_t)BB * LKV * DM;

  bf16* qbf = (bf16*)alloc(nq * 2);  // reused as attn_out after q-proj
  bf16* kbf = (bf16*)alloc(nk * 2);
  bf16* vbf = (bf16*)alloc(nk * 2);
  bf16* WqT = (bf16*)alloc((size_t)DM * DM * 2);
  bf16* WkT = (bf16*)alloc((size_t)DM * DIMG * 2);
  bf16* WvT = (bf16*)alloc((size_t)DM * DIMG * 2);
  bf16* WoT = (bf16*)alloc((size_t)DM * DM * 2);
  bf16* qh  = (bf16*)alloc(nq * 2);
  bf16* kh  = (bf16*)alloc(nkh * 2);
  bf16* Vt  = (bf16*)alloc(nkh * 2);  // [B][H][DK][LKV]
  bf16* attn_out = qbf;

  const int nq4 = (int)(nq / 4), nk4 = (int)(nk / 4);
  cvt_all<<<(nq4 + 2 * nk4 + 255) / 256, 256, 0, stream>>>(q, k, v, qbf, kbf, vbf, nq4, nk4);

  transpose_all<<<dim3(DM / 64, DM / 64, 4), 256, 0, stream>>>(Wq, Wk, Wv, Wo, WqT, WkT, WvT, WoT);

  // q-proj pre-scaled by 1/sqrt(DK) * log2(e): attn softmax runs in log2 domain.
  const float QSCALE = 0.125f * 1.44269504f;
  gemm_one<bf16><<<(BB * LQ / 128) * (DM / 128), 256, 0, stream>>>(
      qbf, WqT, bq, qh, DM, DM, QSCALE);
  gemm_kv<<<(BB * LKV / 128) * (DM / 128) * 2, 256, 0, stream>>>(
      kbf, WkT, bk, kh, vbf, WvT, bv, Vt);

  attn_kernel<<<dim3(LQ / 256, H, BB), 512, 0, stream>>>(qh, kh, Vt, attn_out);

  gemm_one<float><<<(BB * LQ / 128) * (DM / 128), 256, 0, stream>>>(
      attn_out, WoT, bo, out, BB * LQ == 0 ? DM : DM, DM, 1.0f);
}